// Round 5
// baseline (1392.933 us; speedup 1.0000x reference)
//
#include <hip/hip_runtime.h>
#include <math.h>

// RingDilatedAttentionV3: b=1, n=4096, h=12, d=64, fp32.
// Head groups: h in [0,4): identity gather; [4,8): seg=2048, rate=2, off=1;
//              [8,12): seg=4096, rate=4, off=2.
// Flash-attention, 4 lanes per query row (16-float d-slice each),
// K/V 64-key tiles staged in LDS with gather applied inline.

#define NQ 4096
#define NH 12
#define DD 64
#define TK 64       // keys per LDS tile
#define QB 64       // queries per block
#define THREADS 256 // 4 waves; 4 lanes per query

__device__ __forceinline__ int map_src(int h, int j) {
    if (h < 4) {
        return j;                          // dilation 1
    } else if (h < 8) {
        int p = j & 2047;                  // pos within 2048-segment
        int base = j & ~2047;
        return base + (p < 1024 ? 1 + 2 * p : p - 1024);
    } else {
        return (j < 1024) ? (2 + 4 * j) : (j - 1024);
    }
}

__global__ __launch_bounds__(THREADS, 4) void dilated_attn_f32(
    const float* __restrict__ q,
    const float* __restrict__ k,
    const float* __restrict__ v,
    float* __restrict__ out)
{
    __shared__ float k_lds[TK][DD];
    __shared__ float v_lds[TK][DD];

    const int h    = blockIdx.y;            // 0..11
    const int qblk = blockIdx.x;            // 0..63
    const int tid  = threadIdx.x;
    const int qi   = qblk * QB + (tid >> 2);
    const int ds   = (tid & 3) << 4;        // d-slice start: 0/16/32/48

    // Load q slice, pre-scaled by 1/sqrt(64)
    float qreg[16];
    {
        const float* qp = q + ((qi * NH + h) << 6) + ds;
        #pragma unroll
        for (int r = 0; r < 4; ++r) {
            float4 t = *(const float4*)(qp + 4 * r);
            qreg[4*r+0] = t.x * 0.125f;
            qreg[4*r+1] = t.y * 0.125f;
            qreg[4*r+2] = t.z * 0.125f;
            qreg[4*r+3] = t.w * 0.125f;
        }
    }

    float o[16];
    #pragma unroll
    for (int r = 0; r < 16; ++r) o[r] = 0.f;
    float m = -INFINITY, l = 0.f;

    for (int tile = 0; tile < NQ / TK; ++tile) {
        __syncthreads();   // previous tile's LDS reads done before overwrite
        // ---- stage K/V tile (gather applied) ----
        #pragma unroll
        for (int i = 0; i < (TK * DD / 4) / THREADS; ++i) {   // 4 iters
            int f   = tid + THREADS * i;      // float4 index in tile
            int jj  = f >> 4;                 // key slot (0..63)
            int c4  = (f & 15) << 2;          // d offset (0..60)
            int src = map_src(h, tile * TK + jj);
            int off = ((src * NH + h) << 6) + c4;
            *(float4*)(&k_lds[jj][c4]) = *(const float4*)(k + off);
            *(float4*)(&v_lds[jj][c4]) = *(const float4*)(v + off);
        }
        __syncthreads();

        // ---- compute: 4 subtiles of 16 keys ----
        #pragma unroll
        for (int sub = 0; sub < TK / 16; ++sub) {
            float sc[16];
            #pragma unroll
            for (int jj = 0; jj < 16; ++jj) {
                const int kk = sub * 16 + jj;
                // 4 independent accumulators: FMA dep chain depth 4, not 16
                float4 a = *(const float4*)(&k_lds[kk][ds +  0]);
                float4 b = *(const float4*)(&k_lds[kk][ds +  4]);
                float4 c = *(const float4*)(&k_lds[kk][ds +  8]);
                float4 e = *(const float4*)(&k_lds[kk][ds + 12]);
                float s0 = qreg[0]  * a.x, s1 = qreg[1]  * a.y;
                float s2 = qreg[2]  * a.z, s3 = qreg[3]  * a.w;
                s0 = fmaf(qreg[4],  b.x, s0); s1 = fmaf(qreg[5],  b.y, s1);
                s2 = fmaf(qreg[6],  b.z, s2); s3 = fmaf(qreg[7],  b.w, s3);
                s0 = fmaf(qreg[8],  c.x, s0); s1 = fmaf(qreg[9],  c.y, s1);
                s2 = fmaf(qreg[10], c.z, s2); s3 = fmaf(qreg[11], c.w, s3);
                s0 = fmaf(qreg[12], e.x, s0); s1 = fmaf(qreg[13], e.y, s1);
                s2 = fmaf(qreg[14], e.z, s2); s3 = fmaf(qreg[15], e.w, s3);
                float s = (s0 + s1) + (s2 + s3);
                // 4-lane all-reduce -> every lane holds the full dot product
                s += __shfl_xor(s, 1);
                s += __shfl_xor(s, 2);
                sc[jj] = s;
            }
            // online softmax (tree max, branchless rescale, once per 16 keys)
            float t0 = fmaxf(sc[0],  sc[1]),  t1 = fmaxf(sc[2],  sc[3]);
            float t2 = fmaxf(sc[4],  sc[5]),  t3 = fmaxf(sc[6],  sc[7]);
            float t4 = fmaxf(sc[8],  sc[9]),  t5 = fmaxf(sc[10], sc[11]);
            float t6 = fmaxf(sc[12], sc[13]), t7 = fmaxf(sc[14], sc[15]);
            t0 = fmaxf(t0, t1); t2 = fmaxf(t2, t3);
            t4 = fmaxf(t4, t5); t6 = fmaxf(t6, t7);
            float tm = fmaxf(fmaxf(t0, t2), fmaxf(t4, t6));
            float m_new = fmaxf(m, tm);
            float scale = __expf(m - m_new);
            #pragma unroll
            for (int r = 0; r < 16; ++r) o[r] *= scale;
            l *= scale;
            m = m_new;
            #pragma unroll
            for (int jj = 0; jj < 16; ++jj) {
                const int kk = sub * 16 + jj;
                float p = __expf(sc[jj] - m);
                l += p;
                #pragma unroll
                for (int r = 0; r < 16; r += 4) {
                    float4 vv = *(const float4*)(&v_lds[kk][ds + r]);
                    o[r+0] = fmaf(p, vv.x, o[r+0]);
                    o[r+1] = fmaf(p, vv.y, o[r+1]);
                    o[r+2] = fmaf(p, vv.z, o[r+2]);
                    o[r+3] = fmaf(p, vv.w, o[r+3]);
                }
            }
        }
    }

    const float inv_l = 1.f / l;
    float* op = out + ((qi * NH + h) << 6) + ds;
    #pragma unroll
    for (int r = 0; r < 4; ++r) {
        float4 t;
        t.x = o[4*r+0] * inv_l;
        t.y = o[4*r+1] * inv_l;
        t.z = o[4*r+2] * inv_l;
        t.w = o[4*r+3] * inv_l;
        *(float4*)(op + 4 * r) = t;
    }
}

extern "C" void kernel_launch(void* const* d_in, const int* in_sizes, int n_in,
                              void* d_out, int out_size, void* d_ws, size_t ws_size,
                              hipStream_t stream) {
    const float* q = (const float*)d_in[0];
    const float* k = (const float*)d_in[1];
    const float* v = (const float*)d_in[2];
    float* out     = (float*)d_out;

    dim3 grid(NQ / QB, NH);   // 64 x 12 = 768 blocks
    dilated_attn_f32<<<grid, THREADS, 0, stream>>>(q, k, v, out);
}

// Round 6
// 302.987 us; speedup vs baseline: 4.5973x; 4.5973x over previous
//
#include <hip/hip_runtime.h>
#include <hip/hip_bf16.h>
#include <math.h>

// RingDilatedAttentionV3: b=1, n=4096, h=12, d=64, fp32 in/out.
// MFMA flash attention: bf16 16x16x32 MFMA, f32 accum.
// Per block: 64 queries (4 waves x 16 q). KV tiles of 64 keys.
// Swapped QK (S^T = K*Q^T) -> softmax lane-local. PV as O^T = V^T * P.
// K LDS row-major [key][d], V LDS transposed [d][key], P per-wave [q][key].
// All strides 72 bf16 (144B): 16B-aligned rows for ds_read_b128, balanced banks.

#define NQ 4096
#define NH 12
#define DD 64
#define KV 64        // keys per tile
#define STR 72       // LDS row stride in bf16 elems

typedef __attribute__((ext_vector_type(8))) short bf16x8;
typedef __attribute__((ext_vector_type(4))) float f32x4;

__device__ __forceinline__ int map_src(int h, int j) {
    if (h < 4) {
        return j;                          // dilation 1
    } else if (h < 8) {
        int p = j & 2047;                  // seg=2048, rate=2, off=1
        int base = j & ~2047;
        return base + (p < 1024 ? 1 + 2 * p : p - 1024);
    } else {                               // seg=4096, rate=4, off=2
        return (j < 1024) ? (2 + 4 * j) : (j - 1024);
    }
}

__device__ __forceinline__ unsigned pk2(float lo, float hi) {
    __hip_bfloat162 t = __float22bfloat162_rn(float2{lo, hi});
    union { __hip_bfloat162 h; unsigned u; } c;
    c.h = t;
    return c.u;
}

__global__ __launch_bounds__(256, 2) void attn_mfma(
    const float* __restrict__ q,
    const float* __restrict__ k,
    const float* __restrict__ v,
    float* __restrict__ out)
{
    __shared__ __align__(16) unsigned short Ks[KV * STR];      // [key][d]
    __shared__ __align__(16) unsigned short Vt[DD * STR];      // [d][key]
    __shared__ __align__(16) unsigned short Ps[4 * 16 * STR];  // per-wave [q][key]

    const int h    = blockIdx.y;
    const int qblk = blockIdx.x;
    const int tid  = threadIdx.x;
    const int wave = tid >> 6;
    const int lane = tid & 63;
    const int lq   = lane & 15;      // q col within wave / row within frag
    const int g    = lane >> 4;      // 16-lane group

    const int qi = qblk * 64 + wave * 16 + lq;

    // ---- Q B-fragments (col=q=lq, kdim = 8g + j + 32ks), pre-scaled 1/8 ----
    union { bf16x8 v8; unsigned u[4]; } qf[2];
    {
        const float* qp = q + (qi * NH + h) * DD;
        #pragma unroll
        for (int ks = 0; ks < 2; ++ks) {
            float4 a = *(const float4*)(qp + 32 * ks + 8 * g);
            float4 b = *(const float4*)(qp + 32 * ks + 8 * g + 4);
            qf[ks].u[0] = pk2(a.x * 0.125f, a.y * 0.125f);
            qf[ks].u[1] = pk2(a.z * 0.125f, a.w * 0.125f);
            qf[ks].u[2] = pk2(b.x * 0.125f, b.y * 0.125f);
            qf[ks].u[3] = pk2(b.z * 0.125f, b.w * 0.125f);
        }
    }

    f32x4 o[4];
    #pragma unroll
    for (int mf = 0; mf < 4; ++mf) o[mf] = f32x4{0.f, 0.f, 0.f, 0.f};
    float m = -INFINITY, l = 0.f;

    unsigned* Pw = (unsigned*)(Ps + wave * 16 * STR);
    unsigned* Vw = (unsigned*)Vt;

    for (int tile = 0; tile < NQ / KV; ++tile) {
        __syncthreads();
        // ---- stage K tile: [key][d] bf16, coalesced float4 reads ----
        #pragma unroll
        for (int i = 0; i < 4; ++i) {
            int f   = tid + 256 * i;          // 0..1023 float4 slots
            int key = f >> 4;
            int c4  = (f & 15) << 2;          // d base
            int src = map_src(h, tile * KV + key);
            float4 t = *(const float4*)(k + (src * NH + h) * DD + c4);
            uint2 w;
            w.x = pk2(t.x, t.y);
            w.y = pk2(t.z, t.w);
            *(uint2*)((char*)Ks + key * (STR * 2) + c4 * 2) = w;
        }
        // ---- stage V^T: [d][key] bf16; 4 d-rows x key-pair per iter ----
        #pragma unroll
        for (int i = 0; i < 2; ++i) {
            int e2  = tid + 256 * i;          // 0..511
            int d4  = (e2 & 15) << 2;         // d base (4 rows)
            int p   = e2 >> 4;                // key pair 0..31
            int s0  = map_src(h, tile * KV + 2 * p);
            int s1  = map_src(h, tile * KV + 2 * p + 1);
            float4 a = *(const float4*)(v + (s0 * NH + h) * DD + d4);
            float4 b = *(const float4*)(v + (s1 * NH + h) * DD + d4);
            Vw[(d4 + 0) * (STR / 2) + p] = pk2(a.x, b.x);
            Vw[(d4 + 1) * (STR / 2) + p] = pk2(a.y, b.y);
            Vw[(d4 + 2) * (STR / 2) + p] = pk2(a.z, b.z);
            Vw[(d4 + 3) * (STR / 2) + p] = pk2(a.w, b.w);
        }
        __syncthreads();

        // ---- QK^T (swapped): S^T[key][q], key = 16mf + 4g + r, q = lq ----
        f32x4 s[4];
        #pragma unroll
        for (int mf = 0; mf < 4; ++mf) {
            s[mf] = f32x4{0.f, 0.f, 0.f, 0.f};
            #pragma unroll
            for (int ks = 0; ks < 2; ++ks) {
                bf16x8 kf = *(const bf16x8*)(Ks + (16 * mf + lq) * STR + 8 * g + 32 * ks);
                s[mf] = __builtin_amdgcn_mfma_f32_16x16x32_bf16(kf, qf[ks].v8, s[mf], 0, 0, 0);
            }
        }

        // ---- online softmax (16 keys/lane, cross-group via 2 shfl) ----
        float mx0 = fmaxf(fmaxf(s[0].x, s[0].y), fmaxf(s[0].z, s[0].w));
        float mx1 = fmaxf(fmaxf(s[1].x, s[1].y), fmaxf(s[1].z, s[1].w));
        float mx2 = fmaxf(fmaxf(s[2].x, s[2].y), fmaxf(s[2].z, s[2].w));
        float mx3 = fmaxf(fmaxf(s[3].x, s[3].y), fmaxf(s[3].z, s[3].w));
        float tm  = fmaxf(fmaxf(mx0, mx1), fmaxf(mx2, mx3));
        tm = fmaxf(tm, __shfl_xor(tm, 16));
        tm = fmaxf(tm, __shfl_xor(tm, 32));
        float mn = fmaxf(m, tm);
        float sc = __expf(m - mn);   // first tile: exp(-inf)=0
        m = mn;
        l *= sc;
        #pragma unroll
        for (int mf = 0; mf < 4; ++mf) {
            f32x4 p;
            p.x = __expf(s[mf].x - mn);
            p.y = __expf(s[mf].y - mn);
            p.z = __expf(s[mf].z - mn);
            p.w = __expf(s[mf].w - mn);
            l += (p.x + p.y) + (p.z + p.w);
            o[mf] *= sc;
            // P[q=lq][key = 16mf + 4g + 2pi + {0,1}]
            Pw[lq * (STR / 2) + 8 * mf + 2 * g + 0] = pk2(p.x, p.y);
            Pw[lq * (STR / 2) + 8 * mf + 2 * g + 1] = pk2(p.z, p.w);
        }

        // ---- PV: O^T[d][q] += V^T[d][key] * P[key][q] ----
        bf16x8 pf0 = *(const bf16x8*)(Ps + wave * 16 * STR + lq * STR + 8 * g);
        bf16x8 pf1 = *(const bf16x8*)(Ps + wave * 16 * STR + lq * STR + 8 * g + 32);
        #pragma unroll
        for (int mf = 0; mf < 4; ++mf) {
            bf16x8 vf0 = *(const bf16x8*)(Vt + (16 * mf + lq) * STR + 8 * g);
            o[mf] = __builtin_amdgcn_mfma_f32_16x16x32_bf16(vf0, pf0, o[mf], 0, 0, 0);
            bf16x8 vf1 = *(const bf16x8*)(Vt + (16 * mf + lq) * STR + 8 * g + 32);
            o[mf] = __builtin_amdgcn_mfma_f32_16x16x32_bf16(vf1, pf1, o[mf], 0, 0, 0);
        }
    }

    // ---- epilogue: total l across groups, normalize, store ----
    l += __shfl_xor(l, 16);
    l += __shfl_xor(l, 32);
    float inv = 1.f / l;
    float* op = out + (qi * NH + h) * DD;
    #pragma unroll
    for (int mf = 0; mf < 4; ++mf) {
        f32x4 r = o[mf] * inv;                    // d = 16mf + 4g + reg
        *(f32x4*)(op + 16 * mf + 4 * g) = r;
    }
}

extern "C" void kernel_launch(void* const* d_in, const int* in_sizes, int n_in,
                              void* d_out, int out_size, void* d_ws, size_t ws_size,
                              hipStream_t stream) {
    const float* q = (const float*)d_in[0];
    const float* k = (const float*)d_in[1];
    const float* v = (const float*)d_in[2];
    float* out     = (float*)d_out;

    dim3 grid(NQ / 64, NH);   // 64 x 12 = 768 blocks
    attn_mfma<<<grid, 256, 0, stream>>>(q, k, v, out);
}

// Round 8
// 242.734 us; speedup vs baseline: 5.7385x; 1.2482x over previous
//
#include <hip/hip_runtime.h>
#include <hip/hip_bf16.h>
#include <math.h>

// RingDilatedAttentionV3: b=1, n=4096, h=12, d=64, fp32 in/out.
// MFMA flash attention, bf16 16x16x32, f32 accum. 64 q/block (4 waves x 16 q),
// KV tiles of 64 keys. Swapped QK (S^T = K*Q^T) -> lane-local softmax rows.
// PV as O^T = V^T * P with P routed through per-wave LDS.
// Round-7 changes vs round-6 (267us, 3.9e7 bank conflicts):
//  - double-buffered K/V LDS + register prefetch: ONE barrier per tile,
//    global L2 latency hides under compute (T14).
//  - XOR swizzle on Vt & Ps dwords: V^T scatter writes 8-way -> 2-way.
//  - exp2 fold: Q pre-scaled by 0.125*log2e, exp2f instead of __expf.

#define NQ 4096
#define NH 12
#define DD 64
#define KV 64
#define STRD 36            // LDS row stride in dwords (72 bf16, 144B)

typedef __attribute__((ext_vector_type(8))) short bf16x8;
typedef __attribute__((ext_vector_type(4))) float f32x4;

__device__ __forceinline__ int map_src(int h, int j) {
    if (h < 4) {
        return j;                          // dilation 1
    } else if (h < 8) {
        int p = j & 2047;                  // seg=2048, rate=2, off=1
        int base = j & ~2047;
        return base + (p < 1024 ? 1 + 2 * p : p - 1024);
    } else {                               // seg=4096, rate=4, off=2
        return (j < 1024) ? (2 + 4 * j) : (j - 1024);
    }
}

__device__ __forceinline__ unsigned pk2(float lo, float hi) {
    __hip_bfloat162 t = __float22bfloat162_rn(float2{lo, hi});
    union { __hip_bfloat162 h; unsigned u; } c;
    c.h = t;
    return c.u;
}

// Swizzled dword offset within a [row][36-dword] tile. XOR key uses row>>2 so
// the V^T scatter (rows step by 4) spreads across 8 distinct banks.
__device__ __forceinline__ int swz(int row, int p) {
    return row * STRD + (p ^ (((row >> 2) & 7) << 2));
}

struct Pre {
    float4 kq[4];
    float4 va[2], vb[2];
};

__device__ __forceinline__ void stage_load(const float* __restrict__ k,
                                           const float* __restrict__ v,
                                           int h, int tile, int tid, Pre& pr) {
    #pragma unroll
    for (int i = 0; i < 4; ++i) {
        int f   = tid + 256 * i;
        int key = f >> 4;
        int c4  = (f & 15) << 2;
        int src = map_src(h, tile * KV + key);
        pr.kq[i] = *(const float4*)(k + (src * NH + h) * DD + c4);
    }
    #pragma unroll
    for (int i = 0; i < 2; ++i) {
        int e2 = tid + 256 * i;
        int d4 = (e2 & 15) << 2;
        int p  = e2 >> 4;
        int s0 = map_src(h, tile * KV + 2 * p);
        int s1 = map_src(h, tile * KV + 2 * p + 1);
        pr.va[i] = *(const float4*)(v + (s0 * NH + h) * DD + d4);
        pr.vb[i] = *(const float4*)(v + (s1 * NH + h) * DD + d4);
    }
}

__device__ __forceinline__ void stage_write(unsigned short* Ks, unsigned* Vw,
                                            int tid, const Pre& pr) {
    #pragma unroll
    for (int i = 0; i < 4; ++i) {
        int f   = tid + 256 * i;
        int key = f >> 4;
        int c4  = (f & 15) << 2;
        uint2 w;
        w.x = pk2(pr.kq[i].x, pr.kq[i].y);
        w.y = pk2(pr.kq[i].z, pr.kq[i].w);
        *(uint2*)((char*)Ks + key * (STRD * 4) + c4 * 2) = w;
    }
    #pragma unroll
    for (int i = 0; i < 2; ++i) {
        int e2 = tid + 256 * i;
        int d4 = (e2 & 15) << 2;
        int p  = e2 >> 4;
        Vw[swz(d4 + 0, p)] = pk2(pr.va[i].x, pr.vb[i].x);
        Vw[swz(d4 + 1, p)] = pk2(pr.va[i].y, pr.vb[i].y);
        Vw[swz(d4 + 2, p)] = pk2(pr.va[i].z, pr.vb[i].z);
        Vw[swz(d4 + 3, p)] = pk2(pr.va[i].w, pr.vb[i].w);
    }
}

__global__ __launch_bounds__(256, 2) void attn_mfma(
    const float* __restrict__ q,
    const float* __restrict__ k,
    const float* __restrict__ v,
    float* __restrict__ out)
{
    __shared__ __align__(16) unsigned short KsB[2][KV * STRD * 2];  // [key][d]
    __shared__ __align__(16) unsigned short VtB[2][DD * STRD * 2];  // [d][key] swz
    __shared__ __align__(16) unsigned short Ps[4 * 16 * STRD * 2];  // per-wave [q][key] swz

    const int h    = blockIdx.y;
    const int qblk = blockIdx.x;
    const int tid  = threadIdx.x;
    const int wave = tid >> 6;
    const int lane = tid & 63;
    const int lq   = lane & 15;
    const int g    = lane >> 4;

    const int qi = qblk * 64 + wave * 16 + lq;

    // Q B-fragments (col=q=lq, k = 8g + j + 32ks), pre-scaled by 0.125*log2e
    const float qscale = 0.125f * 1.4426950408889634f;
    union { bf16x8 v8; unsigned u[4]; } qf[2];
    {
        const float* qp = q + (qi * NH + h) * DD;
        #pragma unroll
        for (int ks = 0; ks < 2; ++ks) {
            float4 a = *(const float4*)(qp + 32 * ks + 8 * g);
            float4 b = *(const float4*)(qp + 32 * ks + 8 * g + 4);
            qf[ks].u[0] = pk2(a.x * qscale, a.y * qscale);
            qf[ks].u[1] = pk2(a.z * qscale, a.w * qscale);
            qf[ks].u[2] = pk2(b.x * qscale, b.y * qscale);
            qf[ks].u[3] = pk2(b.z * qscale, b.w * qscale);
        }
    }

    f32x4 o[4];
    #pragma unroll
    for (int mf = 0; mf < 4; ++mf) o[mf] = f32x4{0.f, 0.f, 0.f, 0.f};
    float m = -INFINITY, l = 0.f;   // m in log2 units

    unsigned* Pw = (unsigned*)Ps + wave * 16 * STRD;

    // ---- prologue: stage tile 0 ----
    Pre pr;
    stage_load(k, v, h, 0, tid, pr);
    stage_write(KsB[0], (unsigned*)VtB[0], tid, pr);

    for (int tile = 0; tile < NQ / KV; ++tile) {
        const int cur = tile & 1;
        __syncthreads();   // buf[cur] writes visible; prior reads of buf[cur^1] done

        // issue next tile's global loads early (latency hides under compute)
        if (tile + 1 < NQ / KV) stage_load(k, v, h, tile + 1, tid, pr);

        const unsigned short* Ksc = KsB[cur];
        const unsigned short* Vtc = VtB[cur];

        // ---- QK^T (swapped): S^T[key=16mf+4g+r][q=lq], in log2 units ----
        f32x4 s[4];
        #pragma unroll
        for (int mf = 0; mf < 4; ++mf) {
            s[mf] = f32x4{0.f, 0.f, 0.f, 0.f};
            #pragma unroll
            for (int ks = 0; ks < 2; ++ks) {
                bf16x8 kf = *(const bf16x8*)(Ksc + (16 * mf + lq) * (STRD * 2) + 8 * g + 32 * ks);
                s[mf] = __builtin_amdgcn_mfma_f32_16x16x32_bf16(kf, qf[ks].v8, s[mf], 0, 0, 0);
            }
        }

        // ---- online softmax (base-2), 16 keys/lane + 2 shfl ----
        float mx0 = fmaxf(fmaxf(s[0].x, s[0].y), fmaxf(s[0].z, s[0].w));
        float mx1 = fmaxf(fmaxf(s[1].x, s[1].y), fmaxf(s[1].z, s[1].w));
        float mx2 = fmaxf(fmaxf(s[2].x, s[2].y), fmaxf(s[2].z, s[2].w));
        float mx3 = fmaxf(fmaxf(s[3].x, s[3].y), fmaxf(s[3].z, s[3].w));
        float tm  = fmaxf(fmaxf(mx0, mx1), fmaxf(mx2, mx3));
        tm = fmaxf(tm, __shfl_xor(tm, 16));
        tm = fmaxf(tm, __shfl_xor(tm, 32));
        float mn = fmaxf(m, tm);
        float sc = exp2f(m - mn);     // first tile: exp2(-inf) = 0
        m = mn;
        l *= sc;
        #pragma unroll
        for (int mf = 0; mf < 4; ++mf) {
            f32x4 p;
            p.x = exp2f(s[mf].x - mn);
            p.y = exp2f(s[mf].y - mn);
            p.z = exp2f(s[mf].z - mn);
            p.w = exp2f(s[mf].w - mn);
            l += (p.x + p.y) + (p.z + p.w);
            o[mf] *= sc;
            // P[q=lq][keypair 8mf+2g+w], swizzled
            Pw[swz(lq, 8 * mf + 2 * g + 0)] = pk2(p.x, p.y);
            Pw[swz(lq, 8 * mf + 2 * g + 1)] = pk2(p.z, p.w);
        }

        // ---- PV: O^T[d][q] += V^T[d][key] * P[key][q] (swizzled reads) ----
        bf16x8 pf0 = *(const bf16x8*)((const unsigned short*)(Pw + swz(lq, 4 * g)));
        bf16x8 pf1 = *(const bf16x8*)((const unsigned short*)(Pw + swz(lq, 4 * g + 16)));
        #pragma unroll
        for (int mf = 0; mf < 4; ++mf) {
            const int vr = 16 * mf + lq;
            bf16x8 vf0 = *(const bf16x8*)(Vtc + 2 * swz(vr, 4 * g));
            o[mf] = __builtin_amdgcn_mfma_f32_16x16x32_bf16(vf0, pf0, o[mf], 0, 0, 0);
            bf16x8 vf1 = *(const bf16x8*)(Vtc + 2 * swz(vr, 4 * g + 16));
            o[mf] = __builtin_amdgcn_mfma_f32_16x16x32_bf16(vf1, pf1, o[mf], 0, 0, 0);
        }

        // ---- write next tile into the other buffer (no extra barrier) ----
        if (tile + 1 < NQ / KV) stage_write(KsB[cur ^ 1], (unsigned*)VtB[cur ^ 1], tid, pr);
    }

    // ---- epilogue ----
    l += __shfl_xor(l, 16);
    l += __shfl_xor(l, 32);
    float inv = 1.f / l;
    float* op = out + (qi * NH + h) * DD;
    #pragma unroll
    for (int mf = 0; mf < 4; ++mf) {
        f32x4 r = o[mf] * inv;                 // d = 16mf + 4g + reg
        *(f32x4*)(op + 16 * mf + 4 * g) = r;
    }
}

extern "C" void kernel_launch(void* const* d_in, const int* in_sizes, int n_in,
                              void* d_out, int out_size, void* d_ws, size_t ws_size,
                              hipStream_t stream) {
    const float* q = (const float*)d_in[0];
    const float* k = (const float*)d_in[1];
    const float* v = (const float*)d_in[2];
    float* out     = (float*)d_out;

    dim3 grid(NQ / 64, NH);   // 768 blocks = 3 blocks/CU
    attn_mfma<<<grid, 256, 0, stream>>>(q, k, v, out);
}

// Round 9
// 195.774 us; speedup vs baseline: 7.1150x; 1.2399x over previous
//
#include <hip/hip_runtime.h>
#include <hip/hip_bf16.h>
#include <math.h>

// RingDilatedAttentionV3: b=1, n=4096, h=12, d=64, fp32 in/out.
// MFMA flash attention, bf16 16x16x32, f32 accum. 64 q/block (4 waves x 16 q),
// KV tiles of 64 keys. Swapped QK (S^T = K*Q^T) -> lane-local softmax rows.
// PV as O^T = V^T * P with P routed through per-wave LDS.
// Round-9 changes vs round-8 (201us, VALUBusy 68% = VALU-bound):
//  - exp2f (libm, multi-instr) -> __builtin_amdgcn_exp2f (1x v_exp_f32).
//  - incremental gather offsets: +uniform delta per tile, map_src recompute
//    only at tile%16==0 (all dilation-region boundaries land there).
//  - exact defer-rescale: skip o/l/m update when no lane's max grew (sc==1).
//  - v_max3 tree for the 16-score max.

#define NQ 4096
#define NH 12
#define DD 64
#define KV 64
#define NT (NQ / KV)
#define STRD 36            // LDS row stride in dwords (72 bf16, 144B)

#define EXP2 __builtin_amdgcn_exp2f

typedef __attribute__((ext_vector_type(8))) short bf16x8;
typedef __attribute__((ext_vector_type(4))) float f32x4;

__device__ __forceinline__ int map_src(int h, int j) {
    if (h < 4) {
        return j;                          // dilation 1
    } else if (h < 8) {
        int p = j & 2047;                  // seg=2048, rate=2, off=1
        int base = j & ~2047;
        return base + (p < 1024 ? 1 + 2 * p : p - 1024);
    } else {                               // seg=4096, rate=4, off=2
        return (j < 1024) ? (2 + 4 * j) : (j - 1024);
    }
}

__device__ __forceinline__ unsigned pk2(float lo, float hi) {
    __hip_bfloat162 t = __float22bfloat162_rn(float2{lo, hi});
    union { __hip_bfloat162 h; unsigned u; } c;
    c.h = t;
    return c.u;
}

// Swizzled dword offset within a [row][36-dword] tile. XOR key uses row>>2 so
// the V^T scatter (rows step by 4) spreads across 8 distinct banks.
__device__ __forceinline__ int swz(int row, int p) {
    return row * STRD + (p ^ (((row >> 2) & 7) << 2));
}

struct Pre {
    float4 kq[4];
    float4 va[2], vb[2];
};

__global__ __launch_bounds__(256, 2) void attn_mfma(
    const float* __restrict__ q,
    const float* __restrict__ k,
    const float* __restrict__ v,
    float* __restrict__ out)
{
    __shared__ __align__(16) unsigned short KsB[2][KV * STRD * 2];  // [key][d]
    __shared__ __align__(16) unsigned short VtB[2][DD * STRD * 2];  // [d][key] swz
    __shared__ __align__(16) unsigned short Ps[4 * 16 * STRD * 2];  // per-wave [q][key] swz

    const int h    = blockIdx.y;
    const int qblk = blockIdx.x;
    const int tid  = threadIdx.x;
    const int wave = tid >> 6;
    const int lane = tid & 63;
    const int lq   = lane & 15;
    const int g    = lane >> 4;

    const int qi   = qblk * 64 + wave * 16 + lq;
    const int keyK = tid >> 4;          // K rows: keyK + {0,16,32,48}
    const int pV   = tid >> 4;          // V pairs: 2pV+{0,1,32,33}
    const int c4   = (tid & 15) << 2;   // d-offset (floats), same for K and V

    // ---- incremental gather offsets (float-element offsets into k/v) ----
    int offK[4], offV[4];
    auto recompute = [&](int t) {
        const int j0 = t * KV;
        #pragma unroll
        for (int i = 0; i < 4; ++i)
            offK[i] = (map_src(h, j0 + keyK + 16 * i) * NH + h) * DD;
        offV[0] = (map_src(h, j0 + 2 * pV)      * NH + h) * DD;
        offV[1] = (map_src(h, j0 + 2 * pV + 1)  * NH + h) * DD;
        offV[2] = (map_src(h, j0 + 2 * pV + 32) * NH + h) * DD;
        offV[3] = (map_src(h, j0 + 2 * pV + 33) * NH + h) * DD;
    };
    auto advance = [&](int T) {   // move offsets to tile T (T >= 1)
        if ((T & 15) == 0) { recompute(T); return; }
        int d;
        if (h < 4)      d = 64;
        else if (h < 8) d = (((T * KV) & 2047) < 1024) ? 128 : 64;
        else            d = (T < 16) ? 256 : 64;
        d *= NH * DD;
        #pragma unroll
        for (int i = 0; i < 4; ++i) offK[i] += d;
        #pragma unroll
        for (int i = 0; i < 4; ++i) offV[i] += d;
    };

    auto stage_load = [&](Pre& pr) {
        #pragma unroll
        for (int i = 0; i < 4; ++i)
            pr.kq[i] = *(const float4*)(k + offK[i] + c4);
        pr.va[0] = *(const float4*)(v + offV[0] + c4);
        pr.vb[0] = *(const float4*)(v + offV[1] + c4);
        pr.va[1] = *(const float4*)(v + offV[2] + c4);
        pr.vb[1] = *(const float4*)(v + offV[3] + c4);
    };
    auto stage_write = [&](unsigned short* Ks, unsigned* Vw, const Pre& pr) {
        #pragma unroll
        for (int i = 0; i < 4; ++i) {
            uint2 w;
            w.x = pk2(pr.kq[i].x, pr.kq[i].y);
            w.y = pk2(pr.kq[i].z, pr.kq[i].w);
            *(uint2*)((char*)Ks + (keyK + 16 * i) * (STRD * 4) + c4 * 2) = w;
        }
        #pragma unroll
        for (int i = 0; i < 2; ++i) {
            int p = pV + 16 * i;
            Vw[swz(c4 + 0, p)] = pk2(pr.va[i].x, pr.vb[i].x);
            Vw[swz(c4 + 1, p)] = pk2(pr.va[i].y, pr.vb[i].y);
            Vw[swz(c4 + 2, p)] = pk2(pr.va[i].z, pr.vb[i].z);
            Vw[swz(c4 + 3, p)] = pk2(pr.va[i].w, pr.vb[i].w);
        }
    };

    // ---- Q B-fragments (col=q=lq, k = 8g + j + 32ks), scaled 0.125*log2e ----
    const float qscale = 0.125f * 1.4426950408889634f;
    union { bf16x8 v8; unsigned u[4]; } qf[2];
    {
        const float* qp = q + (qi * NH + h) * DD;
        #pragma unroll
        for (int ks = 0; ks < 2; ++ks) {
            float4 a = *(const float4*)(qp + 32 * ks + 8 * g);
            float4 b = *(const float4*)(qp + 32 * ks + 8 * g + 4);
            qf[ks].u[0] = pk2(a.x * qscale, a.y * qscale);
            qf[ks].u[1] = pk2(a.z * qscale, a.w * qscale);
            qf[ks].u[2] = pk2(b.x * qscale, b.y * qscale);
            qf[ks].u[3] = pk2(b.z * qscale, b.w * qscale);
        }
    }

    f32x4 o[4];
    #pragma unroll
    for (int mf = 0; mf < 4; ++mf) o[mf] = f32x4{0.f, 0.f, 0.f, 0.f};
    float m = -INFINITY, l = 0.f;   // m in log2 units

    unsigned* Pw = (unsigned*)Ps + wave * 16 * STRD;

    // ---- prologue: stage tile 0 ----
    Pre pr;
    recompute(0);
    stage_load(pr);
    stage_write(KsB[0], (unsigned*)VtB[0], pr);

    for (int tile = 0; tile < NT; ++tile) {
        const int cur = tile & 1;
        __syncthreads();   // buf[cur] writes visible; prior reads of buf[cur^1] done

        // issue next tile's global loads early (latency hides under compute)
        if (tile + 1 < NT) { advance(tile + 1); stage_load(pr); }

        const unsigned short* Ksc = KsB[cur];
        const unsigned short* Vtc = VtB[cur];

        // ---- QK^T (swapped): S^T[key=16mf+4g+r][q=lq], in log2 units ----
        f32x4 s[4];
        #pragma unroll
        for (int mf = 0; mf < 4; ++mf) {
            s[mf] = f32x4{0.f, 0.f, 0.f, 0.f};
            #pragma unroll
            for (int ks = 0; ks < 2; ++ks) {
                bf16x8 kf = *(const bf16x8*)(Ksc + (16 * mf + lq) * (STRD * 2) + 8 * g + 32 * ks);
                s[mf] = __builtin_amdgcn_mfma_f32_16x16x32_bf16(kf, qf[ks].v8, s[mf], 0, 0, 0);
            }
        }

        // ---- online softmax (base-2): v_max3 tree + 2 shfl + defer-rescale ----
        float u0 = fmaxf(fmaxf(s[0].x, s[0].y), s[0].z);
        float u1 = fmaxf(fmaxf(s[0].w, s[1].x), s[1].y);
        float u2 = fmaxf(fmaxf(s[1].z, s[1].w), s[2].x);
        float u3 = fmaxf(fmaxf(s[2].y, s[2].z), s[2].w);
        float u4 = fmaxf(fmaxf(s[3].x, s[3].y), s[3].z);
        float tm = fmaxf(fmaxf(fmaxf(u0, u1), u2),
                         fmaxf(fmaxf(u3, u4), s[3].w));
        tm = fmaxf(tm, __shfl_xor(tm, 16));
        tm = fmaxf(tm, __shfl_xor(tm, 32));
        if (__any(tm > m)) {           // exact: skipped iff sc==1 for all lanes
            float mn = fmaxf(m, tm);
            float sc = EXP2(m - mn);   // first tile: exp2(-inf) = 0
            m = mn;
            l *= sc;
            #pragma unroll
            for (int mf = 0; mf < 4; ++mf) o[mf] *= sc;
        }
        #pragma unroll
        for (int mf = 0; mf < 4; ++mf) {
            f32x4 p;
            p.x = EXP2(s[mf].x - m);
            p.y = EXP2(s[mf].y - m);
            p.z = EXP2(s[mf].z - m);
            p.w = EXP2(s[mf].w - m);
            l += (p.x + p.y) + (p.z + p.w);
            // P[q=lq][keypair 8mf+2g+w], swizzled
            Pw[swz(lq, 8 * mf + 2 * g + 0)] = pk2(p.x, p.y);
            Pw[swz(lq, 8 * mf + 2 * g + 1)] = pk2(p.z, p.w);
        }

        // ---- PV: O^T[d][q] += V^T[d][key] * P[key][q] (swizzled reads) ----
        bf16x8 pf0 = *(const bf16x8*)((const unsigned short*)(Pw + swz(lq, 4 * g)));
        bf16x8 pf1 = *(const bf16x8*)((const unsigned short*)(Pw + swz(lq, 4 * g + 16)));
        #pragma unroll
        for (int mf = 0; mf < 4; ++mf) {
            const int vr = 16 * mf + lq;
            bf16x8 vf0 = *(const bf16x8*)(Vtc + 2 * swz(vr, 4 * g));
            o[mf] = __builtin_amdgcn_mfma_f32_16x16x32_bf16(vf0, pf0, o[mf], 0, 0, 0);
            bf16x8 vf1 = *(const bf16x8*)(Vtc + 2 * swz(vr, 4 * g + 16));
            o[mf] = __builtin_amdgcn_mfma_f32_16x16x32_bf16(vf1, pf1, o[mf], 0, 0, 0);
        }

        // ---- write next tile into the other buffer (no extra barrier) ----
        if (tile + 1 < NT) stage_write(KsB[cur ^ 1], (unsigned*)VtB[cur ^ 1], pr);
    }

    // ---- epilogue ----
    l += __shfl_xor(l, 16);
    l += __shfl_xor(l, 32);
    float inv = 1.f / l;
    float* op = out + (qi * NH + h) * DD;
    #pragma unroll
    for (int mf = 0; mf < 4; ++mf) {
        f32x4 r = o[mf] * inv;                 // d = 16mf + 4g + reg
        *(f32x4*)(op + 16 * mf + 4 * g) = r;
    }
}

extern "C" void kernel_launch(void* const* d_in, const int* in_sizes, int n_in,
                              void* d_out, int out_size, void* d_ws, size_t ws_size,
                              hipStream_t stream) {
    const float* q = (const float*)d_in[0];
    const float* k = (const float*)d_in[1];
    const float* v = (const float*)d_in[2];
    float* out     = (float*)d_out;

    dim3 grid(NQ / 64, NH);   // 768 blocks = 3 blocks/CU
    attn_mfma<<<grid, 256, 0, stream>>>(q, k, v, out);
}

// Round 10
// 178.731 us; speedup vs baseline: 7.7935x; 1.0954x over previous
//
#include <hip/hip_runtime.h>
#include <hip/hip_bf16.h>
#include <math.h>

// RingDilatedAttentionV3: b=1, n=4096, h=12, d=64, fp32 in/out.
// Round-10 structure:
//  1) prepack kernel: gather (map_src) + f32->bf16 + V-transpose ONCE into
//     d_ws, stored in an XOR-swizzled tile layout (phys dword =
//     row*32 + (c ^ ((row&7)<<2)) within each 64x64 tile).
//  2) attn kernel: global_load_lds(16B) direct staging (no VALU convert, no
//     register round-trip), double-buffered, fragment reads apply the same
//     XOR -> K/V LDS reads conflict-free. Compute loop identical to round 9
//     (swapped QK, lane-local softmax, defer-rescale, exp2, Ps round-trip).

#define NQ 4096
#define NH 12
#define DD 64
#define KV 64
#define NT (NQ / KV)
#define PSTR 36                      // Ps row stride in dwords (pad)
#define TILE_USHORT (KV * DD)        // 4096 ushorts per tile
#define TILE_BYTES  (KV * DD * 2)    // 8192 B per tile
#define EXP2 __builtin_amdgcn_exp2f

typedef __attribute__((ext_vector_type(8))) short bf16x8;
typedef __attribute__((ext_vector_type(4))) float f32x4;
typedef __attribute__((ext_vector_type(4))) unsigned int u32x4;

__device__ __forceinline__ int map_src(int h, int j) {
    if (h < 4) {
        return j;                          // dilation 1
    } else if (h < 8) {
        int p = j & 2047;                  // seg=2048, rate=2, off=1
        int base = j & ~2047;
        return base + (p < 1024 ? 1 + 2 * p : p - 1024);
    } else {                               // seg=4096, rate=4, off=2
        return (j < 1024) ? (2 + 4 * j) : (j - 1024);
    }
}

__device__ __forceinline__ unsigned pk2(float lo, float hi) {
    __hip_bfloat162 t = __float22bfloat162_rn(float2{lo, hi});
    union { __hip_bfloat162 h; unsigned u; } c;
    c.h = t;
    return c.u;
}

// Ps-only swizzle (unchanged from round 9).
__device__ __forceinline__ int swz(int row, int p) {
    return row * PSTR + (p ^ (((row >> 2) & 7) << 2));
}

__device__ __forceinline__ void gload16(const void* g, void* l) {
    __builtin_amdgcn_global_load_lds(
        (const __attribute__((address_space(1))) unsigned int*)g,
        (__attribute__((address_space(3))) unsigned int*)l, 16, 0, 0);
}

// ---------------- pre-pass: gather + bf16 + transpose + swizzle ----------------
__global__ __launch_bounds__(256) void prepack(
    const float* __restrict__ k, const float* __restrict__ v,
    unsigned short* __restrict__ kp, unsigned short* __restrict__ vp)
{
    __shared__ float vt[KV][DD + 1];   // pad 65: transpose reads 2-way max
    const int t = blockIdx.x, h = blockIdx.y, tid = threadIdx.x;
    const int row = tid >> 2, q4 = tid & 3;    // row: key (K/V-read) or d (V-write)
    const int src = map_src(h, t * KV + row);

    // K tile: [key][d] bf16, swizzled dwords
    {
        const float* kr = k + ((size_t)src * NH + h) * DD + 16 * q4;
        float4 a = *(const float4*)(kr + 0);
        float4 b = *(const float4*)(kr + 4);
        float4 c = *(const float4*)(kr + 8);
        float4 d = *(const float4*)(kr + 12);
        unsigned* kb = (unsigned*)(kp + (size_t)(h * NT + t) * TILE_USHORT);
        const int x = (row & 7) << 2;
        u32x4 w0, w1;
        w0.x = pk2(a.x, a.y); w0.y = pk2(a.z, a.w);
        w0.z = pk2(b.x, b.y); w0.w = pk2(b.z, b.w);
        w1.x = pk2(c.x, c.y); w1.y = pk2(c.z, c.w);
        w1.z = pk2(d.x, d.y); w1.w = pk2(d.z, d.w);
        *(u32x4*)(kb + (row << 5) + ((8 * q4) ^ x))     = w0;
        *(u32x4*)(kb + (row << 5) + ((8 * q4 + 4) ^ x)) = w1;
    }
    // V rows -> LDS f32
    {
        const float* vr = v + ((size_t)src * NH + h) * DD + 16 * q4;
        #pragma unroll
        for (int i = 0; i < 16; ++i) vt[row][16 * q4 + i] = vr[i];
    }
    __syncthreads();
    // V^T tile: [d][key-pairs] bf16, swizzled dwords. dword ck = keys {2ck,2ck+1}
    {
        const int d = row, u = q4;
        unsigned* vb = (unsigned*)(vp + (size_t)(h * NT + t) * TILE_USHORT);
        const int x = (d & 7) << 2;
        u32x4 w0, w1;
        w0.x = pk2(vt[16*u +  0][d], vt[16*u +  1][d]);
        w0.y = pk2(vt[16*u +  2][d], vt[16*u +  3][d]);
        w0.z = pk2(vt[16*u +  4][d], vt[16*u +  5][d]);
        w0.w = pk2(vt[16*u +  6][d], vt[16*u +  7][d]);
        w1.x = pk2(vt[16*u +  8][d], vt[16*u +  9][d]);
        w1.y = pk2(vt[16*u + 10][d], vt[16*u + 11][d]);
        w1.z = pk2(vt[16*u + 12][d], vt[16*u + 13][d]);
        w1.w = pk2(vt[16*u + 14][d], vt[16*u + 15][d]);
        *(u32x4*)(vb + (d << 5) + ((8 * u) ^ x))     = w0;
        *(u32x4*)(vb + (d << 5) + ((8 * u + 4) ^ x)) = w1;
    }
}

// ---------------- attention ----------------
__global__ __launch_bounds__(256, 2) void attn_mfma(
    const float* __restrict__ q,
    const unsigned short* __restrict__ kp,
    const unsigned short* __restrict__ vp,
    float* __restrict__ out)
{
    __shared__ __align__(16) unsigned short KsB[2][TILE_USHORT];   // 2 x 8KB
    __shared__ __align__(16) unsigned short VtB[2][TILE_USHORT];   // 2 x 8KB
    __shared__ __align__(16) unsigned short Ps[4 * 16 * PSTR * 2]; // 9.2KB

    const int h    = blockIdx.y;
    const int qblk = blockIdx.x;
    const int tid  = threadIdx.x;
    const int wave = tid >> 6;
    const int lane = tid & 63;
    const int lq   = lane & 15;
    const int g    = lane >> 4;
    const int xk   = (lq & 7) << 2;          // fragment-read XOR key

    const int qi = qblk * 64 + wave * 16 + lq;

    const char* ksrc = (const char*)(kp + (size_t)h * NT * TILE_USHORT);
    const char* vsrc = (const char*)(vp + (size_t)h * NT * TILE_USHORT);
    const int lbase = wave * 2048;           // this wave's LDS byte chunk
    const int csrc  = lbase + lane * 16;     // per-lane global byte offset

    // Q B-fragments (col=q=lq, k = 8g + j + 32ks), scaled 0.125*log2e
    const float qscale = 0.125f * 1.4426950408889634f;
    union { bf16x8 v8; unsigned u[4]; } qf[2];
    {
        const float* qp = q + ((size_t)qi * NH + h) * DD;
        #pragma unroll
        for (int ks = 0; ks < 2; ++ks) {
            float4 a = *(const float4*)(qp + 32 * ks + 8 * g);
            float4 b = *(const float4*)(qp + 32 * ks + 8 * g + 4);
            qf[ks].u[0] = pk2(a.x * qscale, a.y * qscale);
            qf[ks].u[1] = pk2(a.z * qscale, a.w * qscale);
            qf[ks].u[2] = pk2(b.x * qscale, b.y * qscale);
            qf[ks].u[3] = pk2(b.z * qscale, b.w * qscale);
        }
    }

    f32x4 o[4];
    #pragma unroll
    for (int mf = 0; mf < 4; ++mf) o[mf] = f32x4{0.f, 0.f, 0.f, 0.f};
    float m = -INFINITY, l = 0.f;   // m in log2 units

    unsigned* Pw = (unsigned*)Ps + wave * 16 * PSTR;

    // prologue: stage tile 0 (direct global->LDS, 1KB per instruction)
    gload16(ksrc + csrc,        (char*)KsB[0] + lbase);
    gload16(ksrc + csrc + 1024, (char*)KsB[0] + lbase + 1024);
    gload16(vsrc + csrc,        (char*)VtB[0] + lbase);
    gload16(vsrc + csrc + 1024, (char*)VtB[0] + lbase + 1024);

    for (int tile = 0; tile < NT; ++tile) {
        const int cur = tile & 1;
        __syncthreads();   // drains vmcnt: buf[cur] staged; buf[cur^1] reads done

        if (tile + 1 < NT) {   // fire-and-forget prefetch of next tile
            const size_t nb = (size_t)(tile + 1) * TILE_BYTES;
            gload16(ksrc + nb + csrc,        (char*)KsB[cur ^ 1] + lbase);
            gload16(ksrc + nb + csrc + 1024, (char*)KsB[cur ^ 1] + lbase + 1024);
            gload16(vsrc + nb + csrc,        (char*)VtB[cur ^ 1] + lbase);
            gload16(vsrc + nb + csrc + 1024, (char*)VtB[cur ^ 1] + lbase + 1024);
        }

        const unsigned short* Ksc = KsB[cur];
        const unsigned short* Vtc = VtB[cur];

        // ---- QK^T (swapped): S^T[key=16mf+4g+r][q=lq], log2 units ----
        f32x4 s[4];
        #pragma unroll
        for (int mf = 0; mf < 4; ++mf) {
            s[mf] = f32x4{0.f, 0.f, 0.f, 0.f};
            #pragma unroll
            for (int ks = 0; ks < 2; ++ks) {
                bf16x8 kf = *(const bf16x8*)(Ksc + 2 * (((16 * mf + lq) << 5) + ((4 * g + 16 * ks) ^ xk)));
                s[mf] = __builtin_amdgcn_mfma_f32_16x16x32_bf16(kf, qf[ks].v8, s[mf], 0, 0, 0);
            }
        }

        // ---- online softmax: max3 tree + 2 shfl + exact defer-rescale ----
        float u0 = fmaxf(fmaxf(s[0].x, s[0].y), s[0].z);
        float u1 = fmaxf(fmaxf(s[0].w, s[1].x), s[1].y);
        float u2 = fmaxf(fmaxf(s[1].z, s[1].w), s[2].x);
        float u3 = fmaxf(fmaxf(s[2].y, s[2].z), s[2].w);
        float u4 = fmaxf(fmaxf(s[3].x, s[3].y), s[3].z);
        float tm = fmaxf(fmaxf(fmaxf(u0, u1), u2),
                         fmaxf(fmaxf(u3, u4), s[3].w));
        tm = fmaxf(tm, __shfl_xor(tm, 16));
        tm = fmaxf(tm, __shfl_xor(tm, 32));
        if (__any(tm > m)) {           // exact: skipped iff sc==1 for all lanes
            float mn = fmaxf(m, tm);
            float sc = EXP2(m - mn);   // first tile: exp2(-inf) = 0
            m = mn;
            l *= sc;
            #pragma unroll
            for (int mf = 0; mf < 4; ++mf) o[mf] *= sc;
        }
        #pragma unroll
        for (int mf = 0; mf < 4; ++mf) {
            f32x4 p;
            p.x = EXP2(s[mf].x - m);
            p.y = EXP2(s[mf].y - m);
            p.z = EXP2(s[mf].z - m);
            p.w = EXP2(s[mf].w - m);
            l += (p.x + p.y) + (p.z + p.w);
            Pw[swz(lq, 8 * mf + 2 * g + 0)] = pk2(p.x, p.y);
            Pw[swz(lq, 8 * mf + 2 * g + 1)] = pk2(p.z, p.w);
        }

        // ---- PV: O^T[d][q] += V^T[d][key] * P[key][q] ----
        bf16x8 pf0 = *(const bf16x8*)((const unsigned short*)(Pw + swz(lq, 4 * g)));
        bf16x8 pf1 = *(const bf16x8*)((const unsigned short*)(Pw + swz(lq, 4 * g + 16)));
        #pragma unroll
        for (int mf = 0; mf < 4; ++mf) {
            const int vr = 16 * mf + lq;
            bf16x8 vf0 = *(const bf16x8*)(Vtc + 2 * ((vr << 5) + ((4 * g) ^ xk)));
            o[mf] = __builtin_amdgcn_mfma_f32_16x16x32_bf16(vf0, pf0, o[mf], 0, 0, 0);
            bf16x8 vf1 = *(const bf16x8*)(Vtc + 2 * ((vr << 5) + ((4 * g + 16) ^ xk)));
            o[mf] = __builtin_amdgcn_mfma_f32_16x16x32_bf16(vf1, pf1, o[mf], 0, 0, 0);
        }
    }

    // ---- epilogue ----
    l += __shfl_xor(l, 16);
    l += __shfl_xor(l, 32);
    float inv = 1.f / l;
    float* op = out + ((size_t)qi * NH + h) * DD;
    #pragma unroll
    for (int mf = 0; mf < 4; ++mf) {
        f32x4 r = o[mf] * inv;                 // d = 16mf + 4g + reg
        *(f32x4*)(op + 16 * mf + 4 * g) = r;
    }
}

extern "C" void kernel_launch(void* const* d_in, const int* in_sizes, int n_in,
                              void* d_out, int out_size, void* d_ws, size_t ws_size,
                              hipStream_t stream) {
    const float* q = (const float*)d_in[0];
    const float* k = (const float*)d_in[1];
    const float* v = (const float*)d_in[2];
    float* out     = (float*)d_out;

    unsigned short* kp = (unsigned short*)d_ws;                       // 6.29 MB
    unsigned short* vp = kp + (size_t)NH * NT * TILE_USHORT;          // 6.29 MB

    prepack<<<dim3(NT, NH), 256, 0, stream>>>(k, v, kp, vp);
    attn_mfma<<<dim3(NQ / 64, NH), 256, 0, stream>>>(q, kp, vp, out);
}

// Round 12
// 176.823 us; speedup vs baseline: 7.8775x; 1.0108x over previous
//
#include <hip/hip_runtime.h>
#include <hip/hip_bf16.h>
#include <math.h>

// RingDilatedAttentionV3: b=1, n=4096, h=12, d=64, fp32 in/out.
// Round-11 structure:
//  1) prepack kernel (unchanged): gather + f32->bf16 + V-transpose into d_ws,
//     XOR-swizzled tiles (phys dword = row*32 + (c ^ ((row&7)<<2))).
//  2) attn kernel: global_load_lds(16B) staging, double-buffered.
//     Swapped QK (16x16x32). PV now uses 16x16x16 MFMAs whose B-operand
//     layout EXACTLY matches QK's C/D layout -> P stays in registers
//     (Ps LDS buffer, its writes/reads/conflicts and lgkm chain removed).
//     XCD-swizzled 1D grid: same-head blocks share an XCD's L2.

#define NQ 4096
#define NH 12
#define DD 64
#define KV 64
#define NT (NQ / KV)
#define TILE_USHORT (KV * DD)        // 4096 ushorts per tile
#define TILE_BYTES  (KV * DD * 2)    // 8192 B per tile
#define EXP2 __builtin_amdgcn_exp2f

typedef __attribute__((ext_vector_type(8))) short bf16x8;
typedef __attribute__((ext_vector_type(4))) short bf16x4;
typedef __attribute__((ext_vector_type(4))) float f32x4;
typedef __attribute__((ext_vector_type(4))) unsigned int u32x4;

__device__ __forceinline__ int map_src(int h, int j) {
    if (h < 4) {
        return j;                          // dilation 1
    } else if (h < 8) {
        int p = j & 2047;                  // seg=2048, rate=2, off=1
        int base = j & ~2047;
        return base + (p < 1024 ? 1 + 2 * p : p - 1024);
    } else {                               // seg=4096, rate=4, off=2
        return (j < 1024) ? (2 + 4 * j) : (j - 1024);
    }
}

__device__ __forceinline__ unsigned pk2(float lo, float hi) {
    __hip_bfloat162 t = __float22bfloat162_rn(float2{lo, hi});
    union { __hip_bfloat162 h; unsigned u; } c;
    c.h = t;
    return c.u;
}

__device__ __forceinline__ f32x4 mfma16(bf16x4 a, bf16x4 b, f32x4 c) {
#if __has_builtin(__builtin_amdgcn_mfma_f32_16x16x16_bf16)
    return __builtin_amdgcn_mfma_f32_16x16x16_bf16(a, b, c, 0, 0, 0);
#elif __has_builtin(__builtin_amdgcn_mfma_f32_16x16x16bf16_1k)
    return __builtin_amdgcn_mfma_f32_16x16x16bf16_1k(a, b, c, 0, 0, 0);
#else
    f32x4 d;
    asm volatile("v_mfma_f32_16x16x16_bf16 %0, %1, %2, %3"
                 : "=v"(d) : "v"(a), "v"(b), "v"(c));
    return d;
#endif
}

__device__ __forceinline__ void gload16(const void* g, void* l) {
    __builtin_amdgcn_global_load_lds(
        (const __attribute__((address_space(1))) unsigned int*)g,
        (__attribute__((address_space(3))) unsigned int*)l, 16, 0, 0);
}

// ---------------- pre-pass: gather + bf16 + transpose + swizzle ----------------
__global__ __launch_bounds__(256) void prepack(
    const float* __restrict__ k, const float* __restrict__ v,
    unsigned short* __restrict__ kp, unsigned short* __restrict__ vp)
{
    __shared__ float vt[KV][DD + 1];   // pad 65: transpose reads 2-way max
    const int t = blockIdx.x, h = blockIdx.y, tid = threadIdx.x;
    const int row = tid >> 2, q4 = tid & 3;    // row: key (K/V-read) or d (V-write)
    const int src = map_src(h, t * KV + row);

    // K tile: [key][d] bf16, swizzled dwords
    {
        const float* kr = k + ((size_t)src * NH + h) * DD + 16 * q4;
        float4 a = *(const float4*)(kr + 0);
        float4 b = *(const float4*)(kr + 4);
        float4 c = *(const float4*)(kr + 8);
        float4 d = *(const float4*)(kr + 12);
        unsigned* kb = (unsigned*)(kp + (size_t)(h * NT + t) * TILE_USHORT);
        const int x = (row & 7) << 2;
        u32x4 w0, w1;
        w0.x = pk2(a.x, a.y); w0.y = pk2(a.z, a.w);
        w0.z = pk2(b.x, b.y); w0.w = pk2(b.z, b.w);
        w1.x = pk2(c.x, c.y); w1.y = pk2(c.z, c.w);
        w1.z = pk2(d.x, d.y); w1.w = pk2(d.z, d.w);
        *(u32x4*)(kb + (row << 5) + ((8 * q4) ^ x))     = w0;
        *(u32x4*)(kb + (row << 5) + ((8 * q4 + 4) ^ x)) = w1;
    }
    // V rows -> LDS f32
    {
        const float* vr = v + ((size_t)src * NH + h) * DD + 16 * q4;
        #pragma unroll
        for (int i = 0; i < 16; ++i) vt[row][16 * q4 + i] = vr[i];
    }
    __syncthreads();
    // V^T tile: [d][key-pairs] bf16, swizzled dwords. dword ck = keys {2ck,2ck+1}
    {
        const int d = row, u = q4;
        unsigned* vb = (unsigned*)(vp + (size_t)(h * NT + t) * TILE_USHORT);
        const int x = (d & 7) << 2;
        u32x4 w0, w1;
        w0.x = pk2(vt[16*u +  0][d], vt[16*u +  1][d]);
        w0.y = pk2(vt[16*u +  2][d], vt[16*u +  3][d]);
        w0.z = pk2(vt[16*u +  4][d], vt[16*u +  5][d]);
        w0.w = pk2(vt[16*u +  6][d], vt[16*u +  7][d]);
        w1.x = pk2(vt[16*u +  8][d], vt[16*u +  9][d]);
        w1.y = pk2(vt[16*u + 10][d], vt[16*u + 11][d]);
        w1.z = pk2(vt[16*u + 12][d], vt[16*u + 13][d]);
        w1.w = pk2(vt[16*u + 14][d], vt[16*u + 15][d]);
        *(u32x4*)(vb + (d << 5) + ((8 * u) ^ x))     = w0;
        *(u32x4*)(vb + (d << 5) + ((8 * u + 4) ^ x)) = w1;
    }
}

// ---------------- attention ----------------
__global__ __launch_bounds__(256, 3) void attn_mfma(
    const float* __restrict__ q,
    const unsigned short* __restrict__ kp,
    const unsigned short* __restrict__ vp,
    float* __restrict__ out)
{
    __shared__ __align__(16) unsigned short KsB[2][TILE_USHORT];   // 2 x 8KB
    __shared__ __align__(16) unsigned short VtB[2][TILE_USHORT];   // 2 x 8KB

    // XCD-aware swizzle (768 % 8 == 0 -> bijective): each XCD gets 96
    // consecutive virtual blocks = 1.5 heads -> kp/vp L2-resident per XCD.
    const int bid  = blockIdx.x;
    const int virt = (bid & 7) * 96 + (bid >> 3);
    const int h    = virt >> 6;
    const int qblk = virt & 63;

    const int tid  = threadIdx.x;
    const int wave = tid >> 6;
    const int lane = tid & 63;
    const int lq   = lane & 15;
    const int g    = lane >> 4;
    const int xk   = (lq & 7) << 2;          // fragment-read XOR key (dwords)

    const int qi = qblk * 64 + wave * 16 + lq;

    const char* ksrc = (const char*)(kp + (size_t)h * NT * TILE_USHORT);
    const char* vsrc = (const char*)(vp + (size_t)h * NT * TILE_USHORT);
    const int lbase = wave * 2048;           // this wave's LDS byte chunk
    const int csrc  = lbase + lane * 16;     // per-lane global byte offset

    // Q B-fragments (col=q=lq, k = 8g + j + 32ks), scaled 0.125*log2e
    const float qscale = 0.125f * 1.4426950408889634f;
    union { bf16x8 v8; unsigned u[4]; } qf[2];
    {
        const float* qp = q + ((size_t)qi * NH + h) * DD;
        #pragma unroll
        for (int ks = 0; ks < 2; ++ks) {
            float4 a = *(const float4*)(qp + 32 * ks + 8 * g);
            float4 b = *(const float4*)(qp + 32 * ks + 8 * g + 4);
            qf[ks].u[0] = pk2(a.x * qscale, a.y * qscale);
            qf[ks].u[1] = pk2(a.z * qscale, a.w * qscale);
            qf[ks].u[2] = pk2(b.x * qscale, b.y * qscale);
            qf[ks].u[3] = pk2(b.z * qscale, b.w * qscale);
        }
    }

    f32x4 o[4];
    #pragma unroll
    for (int mo = 0; mo < 4; ++mo) o[mo] = f32x4{0.f, 0.f, 0.f, 0.f};
    float m = -INFINITY, l = 0.f;   // m in log2 units

    // prologue: stage tile 0 (direct global->LDS, 1KB per instruction)
    gload16(ksrc + csrc,        (char*)KsB[0] + lbase);
    gload16(ksrc + csrc + 1024, (char*)KsB[0] + lbase + 1024);
    gload16(vsrc + csrc,        (char*)VtB[0] + lbase);
    gload16(vsrc + csrc + 1024, (char*)VtB[0] + lbase + 1024);

    for (int tile = 0; tile < NT; ++tile) {
        const int cur = tile & 1;
        __syncthreads();   // drains vmcnt: buf[cur] staged; buf[cur^1] reads done

        if (tile + 1 < NT) {   // fire-and-forget prefetch of next tile
            const size_t nb = (size_t)(tile + 1) * TILE_BYTES;
            gload16(ksrc + nb + csrc,        (char*)KsB[cur ^ 1] + lbase);
            gload16(ksrc + nb + csrc + 1024, (char*)KsB[cur ^ 1] + lbase + 1024);
            gload16(vsrc + nb + csrc,        (char*)VtB[cur ^ 1] + lbase);
            gload16(vsrc + nb + csrc + 1024, (char*)VtB[cur ^ 1] + lbase + 1024);
        }

        const unsigned short* Ksc = KsB[cur];
        const unsigned* Vtd = (const unsigned*)VtB[cur];

        // ---- QK^T (swapped): S^T[key=16mf+4g+r][q=lq], log2 units ----
        f32x4 s[4];
        #pragma unroll
        for (int mf = 0; mf < 4; ++mf) {
            s[mf] = f32x4{0.f, 0.f, 0.f, 0.f};
            #pragma unroll
            for (int ks = 0; ks < 2; ++ks) {
                bf16x8 kf = *(const bf16x8*)(Ksc + 2 * (((16 * mf + lq) << 5) + ((4 * g + 16 * ks) ^ xk)));
                s[mf] = __builtin_amdgcn_mfma_f32_16x16x32_bf16(kf, qf[ks].v8, s[mf], 0, 0, 0);
            }
        }

        // ---- online softmax: max3 tree + 2 shfl + exact defer-rescale ----
        float u0 = fmaxf(fmaxf(s[0].x, s[0].y), s[0].z);
        float u1 = fmaxf(fmaxf(s[0].w, s[1].x), s[1].y);
        float u2 = fmaxf(fmaxf(s[1].z, s[1].w), s[2].x);
        float u3 = fmaxf(fmaxf(s[2].y, s[2].z), s[2].w);
        float u4 = fmaxf(fmaxf(s[3].x, s[3].y), s[3].z);
        float tm = fmaxf(fmaxf(fmaxf(u0, u1), u2),
                         fmaxf(fmaxf(u3, u4), s[3].w));
        tm = fmaxf(tm, __shfl_xor(tm, 16));
        tm = fmaxf(tm, __shfl_xor(tm, 32));
        if (__any(tm > m)) {           // exact: skipped iff sc==1 for all lanes
            float mn = fmaxf(m, tm);
            float sc = EXP2(m - mn);   // first tile: exp2(-inf) = 0
            m = mn;
            l *= sc;
            #pragma unroll
            for (int mo = 0; mo < 4; ++mo) o[mo] *= sc;
        }
        // P in registers: quadrant mf of S^T IS the B-operand of a 16x16x16
        // MFMA (lane supplies B[k=4g+j][col=lq] = keys 16mf+4g+{0..3}, q=lq).
        union { unsigned u[2]; bf16x4 h; } pf[4];
        #pragma unroll
        for (int mf = 0; mf < 4; ++mf) {
            f32x4 p;
            p.x = EXP2(s[mf].x - m);
            p.y = EXP2(s[mf].y - m);
            p.z = EXP2(s[mf].z - m);
            p.w = EXP2(s[mf].w - m);
            l += (p.x + p.y) + (p.z + p.w);
            pf[mf].u[0] = pk2(p.x, p.y);
            pf[mf].u[1] = pk2(p.z, p.w);
        }

        // ---- PV: O^T[16mo+4g+r][lq] += V^T[16mo+lq][16mf+4g+j] * P ----
        #pragma unroll
        for (int mf = 0; mf < 4; ++mf) {
            #pragma unroll
            for (int mo = 0; mo < 4; ++mo) {
                const int vr = 16 * mo + lq;
                bf16x4 vf = *(const bf16x4*)(Vtd + ((vr << 5) + ((8 * mf + 2 * g) ^ xk)));
                o[mo] = mfma16(vf, pf[mf].h, o[mo]);
            }
        }
    }

    // ---- epilogue ----
    l += __shfl_xor(l, 16);
    l += __shfl_xor(l, 32);
    float inv = 1.f / l;
    float* op = out + ((size_t)qi * NH + h) * DD;
    #pragma unroll
    for (int mo = 0; mo < 4; ++mo) {
        f32x4 r = o[mo] * inv;                 // d = 16mo + 4g + reg
        *(f32x4*)(op + 16 * mo + 4 * g) = r;
    }
}

extern "C" void kernel_launch(void* const* d_in, const int* in_sizes, int n_in,
                              void* d_out, int out_size, void* d_ws, size_t ws_size,
                              hipStream_t stream) {
    const float* q = (const float*)d_in[0];
    const float* k = (const float*)d_in[1];
    const float* v = (const float*)d_in[2];
    float* out     = (float*)d_out;

    unsigned short* kp = (unsigned short*)d_ws;                       // 6.29 MB
    unsigned short* vp = kp + (size_t)NH * NT * TILE_USHORT;          // 6.29 MB

    prepack<<<dim3(NT, NH), 256, 0, stream>>>(k, v, kp, vp);
    attn_mfma<<<dim3(NT * NH), 256, 0, stream>>>(q, kp, vp, out);
}

// Round 13
// 171.502 us; speedup vs baseline: 8.1220x; 1.0310x over previous
//
#include <hip/hip_runtime.h>
#include <hip/hip_bf16.h>
#include <math.h>

// RingDilatedAttentionV3: b=1, n=4096, h=12, d=64, fp32 in/out.
// Round-13 structure (delta vs round-12: V-swizzle gains row-bit3 -> bit1):
//  1) prepack: gather + f32->bf16 + V-transpose into d_ws.
//     K tiles: phys dword = row*32 + (c ^ ((row&7)<<2))          [unchanged]
//     V tiles: phys dword = row*32 + (c ^ (((row&7)<<2)|(((row>>3)&1)<<1)))
//     -> the attn b64 V-read has lanes lq and lq+8 on DIFFERENT bank pairs
//        (was the 2x per-quarter serialization behind 1.26e7 conflicts).
//  2) attn: global_load_lds(16B) staging, double-buffered, XCD-swizzled grid.
//     Swapped QK (16x16x32); PV via 16x16x16 MFMAs with P in registers.

#define NQ 4096
#define NH 12
#define DD 64
#define KV 64
#define NT (NQ / KV)
#define TILE_USHORT (KV * DD)        // 4096 ushorts per tile
#define TILE_BYTES  (KV * DD * 2)    // 8192 B per tile
#define EXP2 __builtin_amdgcn_exp2f

typedef __attribute__((ext_vector_type(8))) short bf16x8;
typedef __attribute__((ext_vector_type(4))) short bf16x4;
typedef __attribute__((ext_vector_type(4))) float f32x4;
typedef __attribute__((ext_vector_type(4))) unsigned int u32x4;

__device__ __forceinline__ int map_src(int h, int j) {
    if (h < 4) {
        return j;                          // dilation 1
    } else if (h < 8) {
        int p = j & 2047;                  // seg=2048, rate=2, off=1
        int base = j & ~2047;
        return base + (p < 1024 ? 1 + 2 * p : p - 1024);
    } else {                               // seg=4096, rate=4, off=2
        return (j < 1024) ? (2 + 4 * j) : (j - 1024);
    }
}

__device__ __forceinline__ unsigned pk2(float lo, float hi) {
    __hip_bfloat162 t = __float22bfloat162_rn(float2{lo, hi});
    union { __hip_bfloat162 h; unsigned u; } c;
    c.h = t;
    return c.u;
}

__device__ __forceinline__ f32x4 mfma16(bf16x4 a, bf16x4 b, f32x4 c) {
#if __has_builtin(__builtin_amdgcn_mfma_f32_16x16x16_bf16)
    return __builtin_amdgcn_mfma_f32_16x16x16_bf16(a, b, c, 0, 0, 0);
#elif __has_builtin(__builtin_amdgcn_mfma_f32_16x16x16bf16_1k)
    return __builtin_amdgcn_mfma_f32_16x16x16bf16_1k(a, b, c, 0, 0, 0);
#else
    f32x4 d;
    asm volatile("v_mfma_f32_16x16x16_bf16 %0, %1, %2, %3"
                 : "=v"(d) : "v"(a), "v"(b), "v"(c));
    return d;
#endif
}

__device__ __forceinline__ void gload16(const void* g, void* l) {
    __builtin_amdgcn_global_load_lds(
        (const __attribute__((address_space(1))) unsigned int*)g,
        (__attribute__((address_space(3))) unsigned int*)l, 16, 0, 0);
}

// ---------------- pre-pass: gather + bf16 + transpose + swizzle ----------------
__global__ __launch_bounds__(256) void prepack(
    const float* __restrict__ k, const float* __restrict__ v,
    unsigned short* __restrict__ kp, unsigned short* __restrict__ vp)
{
    __shared__ float vt[KV][DD + 1];   // pad 65: transpose accesses <=2-way
    const int t = blockIdx.x, h = blockIdx.y, tid = threadIdx.x;
    const int row = tid >> 2, q4 = tid & 3;    // row: key (K/V-read) or d (V-write)
    const int src = map_src(h, t * KV + row);

    // K tile: [key][d] bf16, swizzled dwords (key = (row&7)<<2, unchanged)
    {
        const float* kr = k + ((size_t)src * NH + h) * DD + 16 * q4;
        float4 a = *(const float4*)(kr + 0);
        float4 b = *(const float4*)(kr + 4);
        float4 c = *(const float4*)(kr + 8);
        float4 d = *(const float4*)(kr + 12);
        unsigned* kb = (unsigned*)(kp + (size_t)(h * NT + t) * TILE_USHORT);
        const int x = (row & 7) << 2;
        u32x4 w0, w1;
        w0.x = pk2(a.x, a.y); w0.y = pk2(a.z, a.w);
        w0.z = pk2(b.x, b.y); w0.w = pk2(b.z, b.w);
        w1.x = pk2(c.x, c.y); w1.y = pk2(c.z, c.w);
        w1.z = pk2(d.x, d.y); w1.w = pk2(d.z, d.w);
        *(u32x4*)(kb + (row << 5) + ((8 * q4) ^ x))     = w0;
        *(u32x4*)(kb + (row << 5) + ((8 * q4 + 4) ^ x)) = w1;
    }
    // V rows -> LDS f32
    {
        const float* vr = v + ((size_t)src * NH + h) * DD + 16 * q4;
        #pragma unroll
        for (int i = 0; i < 16; ++i) vt[row][16 * q4 + i] = vr[i];
    }
    __syncthreads();
    // V^T tile: [d][key-pairs] bf16. Swizzle key includes row bit3 -> bit1,
    // so stores are 8B uint2 (16B vectors can't survive the bit-1 XOR).
    // dword col c holds keys {2c, 2c+1}.
    {
        const int d = row, u = q4;
        unsigned* vb = (unsigned*)(vp + (size_t)(h * NT + t) * TILE_USHORT);
        const int key = ((d & 7) << 2) | (((d >> 3) & 1) << 1);
        #pragma unroll
        for (int tt = 0; tt < 4; ++tt) {
            uint2 w;
            w.x = pk2(vt[16 * u + 4 * tt + 0][d], vt[16 * u + 4 * tt + 1][d]);
            w.y = pk2(vt[16 * u + 4 * tt + 2][d], vt[16 * u + 4 * tt + 3][d]);
            *(uint2*)(vb + (d << 5) + ((8 * u + 2 * tt) ^ key)) = w;
        }
    }
}

// ---------------- attention ----------------
__global__ __launch_bounds__(256, 3) void attn_mfma(
    const float* __restrict__ q,
    const unsigned short* __restrict__ kp,
    const unsigned short* __restrict__ vp,
    float* __restrict__ out)
{
    __shared__ __align__(16) unsigned short KsB[2][TILE_USHORT];   // 2 x 8KB
    __shared__ __align__(16) unsigned short VtB[2][TILE_USHORT];   // 2 x 8KB

    // XCD-aware swizzle (768 % 8 == 0 -> bijective): each XCD gets 96
    // consecutive virtual blocks = 1.5 heads -> kp/vp L2-resident per XCD.
    const int bid  = blockIdx.x;
    const int virt = (bid & 7) * 96 + (bid >> 3);
    const int h    = virt >> 6;
    const int qblk = virt & 63;

    const int tid  = threadIdx.x;
    const int wave = tid >> 6;
    const int lane = tid & 63;
    const int lq   = lane & 15;
    const int g    = lane >> 4;
    const int xk   = (lq & 7) << 2;                      // K-read XOR (dwords)
    const int xkv  = xk | ((lq >> 3) << 1);              // V-read XOR (dwords)

    const int qi = qblk * 64 + wave * 16 + lq;

    const char* ksrc = (const char*)(kp + (size_t)h * NT * TILE_USHORT);
    const char* vsrc = (const char*)(vp + (size_t)h * NT * TILE_USHORT);
    const int lbase = wave * 2048;           // this wave's LDS byte chunk
    const int csrc  = lbase + lane * 16;     // per-lane global byte offset

    // Q B-fragments (col=q=lq, k = 8g + j + 32ks), scaled 0.125*log2e
    const float qscale = 0.125f * 1.4426950408889634f;
    union { bf16x8 v8; unsigned u[4]; } qf[2];
    {
        const float* qp = q + ((size_t)qi * NH + h) * DD;
        #pragma unroll
        for (int ks = 0; ks < 2; ++ks) {
            float4 a = *(const float4*)(qp + 32 * ks + 8 * g);
            float4 b = *(const float4*)(qp + 32 * ks + 8 * g + 4);
            qf[ks].u[0] = pk2(a.x * qscale, a.y * qscale);
            qf[ks].u[1] = pk2(a.z * qscale, a.w * qscale);
            qf[ks].u[2] = pk2(b.x * qscale, b.y * qscale);
            qf[ks].u[3] = pk2(b.z * qscale, b.w * qscale);
        }
    }

    f32x4 o[4];
    #pragma unroll
    for (int mo = 0; mo < 4; ++mo) o[mo] = f32x4{0.f, 0.f, 0.f, 0.f};
    float m = -INFINITY, l = 0.f;   // m in log2 units

    // prologue: stage tile 0 (direct global->LDS, 1KB per instruction)
    gload16(ksrc + csrc,        (char*)KsB[0] + lbase);
    gload16(ksrc + csrc + 1024, (char*)KsB[0] + lbase + 1024);
    gload16(vsrc + csrc,        (char*)VtB[0] + lbase);
    gload16(vsrc + csrc + 1024, (char*)VtB[0] + lbase + 1024);

    for (int tile = 0; tile < NT; ++tile) {
        const int cur = tile & 1;
        __syncthreads();   // drains vmcnt: buf[cur] staged; buf[cur^1] reads done

        if (tile + 1 < NT) {   // fire-and-forget prefetch of next tile
            const size_t nb = (size_t)(tile + 1) * TILE_BYTES;
            gload16(ksrc + nb + csrc,        (char*)KsB[cur ^ 1] + lbase);
            gload16(ksrc + nb + csrc + 1024, (char*)KsB[cur ^ 1] + lbase + 1024);
            gload16(vsrc + nb + csrc,        (char*)VtB[cur ^ 1] + lbase);
            gload16(vsrc + nb + csrc + 1024, (char*)VtB[cur ^ 1] + lbase + 1024);
        }

        const unsigned short* Ksc = KsB[cur];
        const unsigned* Vtd = (const unsigned*)VtB[cur];

        // ---- QK^T (swapped): S^T[key=16mf+4g+r][q=lq], log2 units ----
        f32x4 s[4];
        #pragma unroll
        for (int mf = 0; mf < 4; ++mf) {
            s[mf] = f32x4{0.f, 0.f, 0.f, 0.f};
            #pragma unroll
            for (int ks = 0; ks < 2; ++ks) {
                bf16x8 kf = *(const bf16x8*)(Ksc + 2 * (((16 * mf + lq) << 5) + ((4 * g + 16 * ks) ^ xk)));
                s[mf] = __builtin_amdgcn_mfma_f32_16x16x32_bf16(kf, qf[ks].v8, s[mf], 0, 0, 0);
            }
        }

        // ---- online softmax: max3 tree + 2 shfl + exact defer-rescale ----
        float u0 = fmaxf(fmaxf(s[0].x, s[0].y), s[0].z);
        float u1 = fmaxf(fmaxf(s[0].w, s[1].x), s[1].y);
        float u2 = fmaxf(fmaxf(s[1].z, s[1].w), s[2].x);
        float u3 = fmaxf(fmaxf(s[2].y, s[2].z), s[2].w);
        float u4 = fmaxf(fmaxf(s[3].x, s[3].y), s[3].z);
        float tm = fmaxf(fmaxf(fmaxf(u0, u1), u2),
                         fmaxf(fmaxf(u3, u4), s[3].w));
        tm = fmaxf(tm, __shfl_xor(tm, 16));
        tm = fmaxf(tm, __shfl_xor(tm, 32));
        if (__any(tm > m)) {           // exact: skipped iff sc==1 for all lanes
            float mn = fmaxf(m, tm);
            float sc = EXP2(m - mn);   // first tile: exp2(-inf) = 0
            m = mn;
            l *= sc;
            #pragma unroll
            for (int mo = 0; mo < 4; ++mo) o[mo] *= sc;
        }
        // P in registers: quadrant mf of S^T IS the B-operand of a 16x16x16
        // MFMA (lane supplies B[k=4g+j][col=lq] = keys 16mf+4g+{0..3}, q=lq).
        union { unsigned u[2]; bf16x4 h; } pf[4];
        #pragma unroll
        for (int mf = 0; mf < 4; ++mf) {
            f32x4 p;
            p.x = EXP2(s[mf].x - m);
            p.y = EXP2(s[mf].y - m);
            p.z = EXP2(s[mf].z - m);
            p.w = EXP2(s[mf].w - m);
            l += (p.x + p.y) + (p.z + p.w);
            pf[mf].u[0] = pk2(p.x, p.y);
            pf[mf].u[1] = pk2(p.z, p.w);
        }

        // ---- PV: O^T[16mo+4g+r][lq] += V^T[16mo+lq][16mf+4g+j] * P ----
        #pragma unroll
        for (int mf = 0; mf < 4; ++mf) {
            #pragma unroll
            for (int mo = 0; mo < 4; ++mo) {
                const int vr = 16 * mo + lq;
                bf16x4 vf = *(const bf16x4*)(Vtd + ((vr << 5) + ((8 * mf + 2 * g) ^ xkv)));
                o[mo] = mfma16(vf, pf[mf].h, o[mo]);
            }
        }
    }

    // ---- epilogue ----
    l += __shfl_xor(l, 16);
    l += __shfl_xor(l, 32);
    float inv = 1.f / l;
    float* op = out + ((size_t)qi * NH + h) * DD;
    #pragma unroll
    for (int mo = 0; mo < 4; ++mo) {
        f32x4 r = o[mo] * inv;                 // d = 16mo + 4g + reg
        *(f32x4*)(op + 16 * mo + 4 * g) = r;
    }
}

extern "C" void kernel_launch(void* const* d_in, const int* in_sizes, int n_in,
                              void* d_out, int out_size, void* d_ws, size_t ws_size,
                              hipStream_t stream) {
    const float* q = (const float*)d_in[0];
    const float* k = (const float*)d_in[1];
    const float* v = (const float*)d_in[2];
    float* out     = (float*)d_out;

    unsigned short* kp = (unsigned short*)d_ws;                       // 6.29 MB
    unsigned short* vp = kp + (size_t)NH * NT * TILE_USHORT;          // 6.29 MB

    prepack<<<dim3(NT, NH), 256, 0, stream>>>(k, v, kp, vp);
    attn_mfma<<<dim3(NT * NH), 256, 0, stream>>>(q, kp, vp, out);
}